// Round 7
// baseline (165.899 us; speedup 1.0000x reference)
//
#include <hip/hip_runtime.h>

// VQ-VAE vector quantizer. N=131072 rows (32*64*64), D=64, K=512.
// X: NCHW f32 (32,64,64,64); W: (512,64) f32.
// out: [0]=loss, [1..8388609)=quantized NCHW, [8388609]=perplexity,
//      [8388610..)=one-hot encodings [131072][512].
#define BHW 262144
#define OUT_Q_OFF 1
#define OUT_P_OFF 8388609
#define OUT_E_OFF 8388610

// ws layout (4-byte words):
// [0..256)      loss partial slots (f32)   -- memset 0
// [256..768)    counts (u32)               -- memset 0
// [768..1280)   wsq = ||e_k||^2 (f32)
// [1280..17664) bf16 codebook B-fragments, PRE-SCALED by -2: [tn=32][j=2][lane=64] x 8
// [17664..148736) per-row argmin indices (i32)
#define IDX_W 17664

typedef __attribute__((ext_vector_type(8))) short short8;
typedef __attribute__((ext_vector_type(4))) float f32x4;
typedef __attribute__((ext_vector_type(2))) float f32x2;

__device__ __forceinline__ unsigned short f2bf(float f) {
    union { float f; unsigned u; } c; c.f = f;
    unsigned r = (c.u + 0x7FFFu + ((c.u >> 16) & 1u)) >> 16;  // RNE
    return (unsigned short)r;
}

__global__ __launch_bounds__(512) void vq_init(const float* __restrict__ W, float* __restrict__ ws) {
    const int tid = blockIdx.x * 512 + threadIdx.x;
    if (tid < 512) {
        const float4* W4 = (const float4*)W;
        float s = 0.f;
#pragma unroll
        for (int i = 0; i < 16; ++i) {
            float4 v = W4[tid * 16 + i];
            s = fmaf(v.x, v.x, s); s = fmaf(v.y, v.y, s);
            s = fmaf(v.z, v.z, s); s = fmaf(v.w, v.w, s);
        }
        ws[768 + tid] = s;
    } else {
        // B-fragment pre-swizzle (scaled by -2): chunk c -> (tn, j, lane)
        const int c  = tid - 512;            // 0..4095
        const int l  = c & 63;
        const int j  = (c >> 6) & 1;
        const int tn = c >> 7;
        const int n  = tn * 16 + (l & 15);
        const int k0 = j * 32 + ((l >> 4) & 3) * 8;
        const float* src = W + n * 64 + k0;
        unsigned h0 = f2bf(-2.f * src[0]) | ((unsigned)f2bf(-2.f * src[1]) << 16);
        unsigned h1 = f2bf(-2.f * src[2]) | ((unsigned)f2bf(-2.f * src[3]) << 16);
        unsigned h2 = f2bf(-2.f * src[4]) | ((unsigned)f2bf(-2.f * src[5]) << 16);
        unsigned h3 = f2bf(-2.f * src[6]) | ((unsigned)f2bf(-2.f * src[7]) << 16);
        uint4* dst = (uint4*)(ws + 1280);
        dst[c] = make_uint4(h0, h1, h2, h3);
    }
}

// K_score: one wave per block, 16 rows. MFMA argmin -> idx/hist/quantized/loss.
// NO encodings traffic here.
__global__ __launch_bounds__(64) void vq_score(const float* __restrict__ X,
                                               const float* __restrict__ W,
                                               float* __restrict__ out,
                                               float* __restrict__ ws) {
    const int l    = threadIdx.x;        // 0..63
    const int nlow = l & 15;
    const int kg   = l >> 4;
    const int rowbase = blockIdx.x * 16; // 16 consecutive rows, same (b,h)
    const int b  = rowbase >> 12;
    const int h  = (rowbase >> 6) & 63;
    const int w0 = rowbase & 63;

    // this lane's x row (A-frag row = nlow), dims (kg,e); kept for epilogue
    const float* xr = X + (size_t)b * BHW + (size_t)h * 64 + (w0 + nlow);
    float xf[16];
#pragma unroll
    for (int e = 0; e < 8; ++e) xf[e]     = xr[(size_t)(kg * 8 + e) * 4096];
#pragma unroll
    for (int e = 0; e < 8; ++e) xf[8 + e] = xr[(size_t)(32 + kg * 8 + e) * 4096];
    short8 a0, a1;
#pragma unroll
    for (int e = 0; e < 8; ++e) { a0[e] = (short)f2bf(xf[e]); a1[e] = (short)f2bf(xf[8 + e]); }

    // scan all 512 codes: score = wsq (C-init) + (-2e)·x via MFMA
    const short8* __restrict__ B8  = (const short8*)(ws + 1280);
    const float*  __restrict__ wsq = ws + 768;
    float bS[4]; int bK[4];
#pragma unroll
    for (int r = 0; r < 4; ++r) { bS[r] = 3.4e38f; bK[r] = 0; }

#pragma unroll 2
    for (int tn = 0; tn < 32; ++tn) {
        short8 f0 = B8[tn * 128 + l];
        short8 f1 = B8[tn * 128 + 64 + l];
        const float wq = wsq[tn * 16 + nlow];
        f32x4 acc = {wq, wq, wq, wq};
        acc = __builtin_amdgcn_mfma_f32_16x16x32_bf16(a0, f0, acc, 0, 0, 0);
        acc = __builtin_amdgcn_mfma_f32_16x16x32_bf16(a1, f1, acc, 0, 0, 0);
        const int n = tn * 16 + nlow;
#pragma unroll
        for (int r = 0; r < 4; ++r) {
            if (acc[r] < bS[r]) { bS[r] = acc[r]; bK[r] = n; }
        }
    }
    // butterfly min-reduce over 16 col-lanes per kg group (lowest-k tiebreak)
#pragma unroll
    for (int r = 0; r < 4; ++r) {
#pragma unroll
        for (int mask = 1; mask <= 8; mask <<= 1) {
            float os = __shfl_xor(bS[r], mask);
            int   ok = __shfl_xor(bK[r], mask);
            if (os < bS[r] || (os == bS[r] && ok < bK[r])) { bS[r] = os; bK[r] = ok; }
        }
    }

    // per-row best broadcast; index store + histogram
    int rowBk = 0;   // best for this lane's own row (nlow)
    int myBk  = 0;   // best for row l (lanes 0..15)
#pragma unroll
    for (int m = 0; m < 16; ++m) {
        int bkm = __shfl(bK[m & 3], (m >> 2) * 16);
        if (nlow == m) rowBk = bkm;
        if (l == m)    myBk = bkm;
    }
    if (l < 16) {
        ((int*)ws)[IDX_W + rowbase + l] = myBk;
        atomicAdd((unsigned*)ws + 256 + myBk, 1u);
    }

    // quantized_st + loss partials (x register-resident; W row L2-hot)
    const float4* W4 = (const float4*)W;
    float4 q0 = W4[rowBk * 16 + kg * 2];
    float4 q1 = W4[rowBk * 16 + kg * 2 + 1];
    float4 q2 = W4[rowBk * 16 + 8 + kg * 2];
    float4 q3 = W4[rowBk * 16 + 8 + kg * 2 + 1];
    float qv[16] = {q0.x, q0.y, q0.z, q0.w, q1.x, q1.y, q1.z, q1.w,
                    q2.x, q2.y, q2.z, q2.w, q3.x, q3.y, q3.z, q3.w};
    float lsum = 0.f;
    float* op = out + OUT_Q_OFF + (size_t)b * BHW + (size_t)h * 64 + (w0 + nlow);
#pragma unroll
    for (int e = 0; e < 8; ++e) {
        float d0 = qv[e] - xf[e];
        lsum = fmaf(d0, d0, lsum);
        op[(size_t)(kg * 8 + e) * 4096] = xf[e] + d0;
        float d1 = qv[8 + e] - xf[8 + e];
        lsum = fmaf(d1, d1, lsum);
        op[(size_t)(32 + kg * 8 + e) * 4096] = xf[8 + e] + d1;
    }

    // loss wave-reduce; spread atomics over 256 slots
#pragma unroll
    for (int off = 32; off >= 1; off >>= 1) lsum += __shfl_down(lsum, off);
    if (l == 0) atomicAdd(ws + (blockIdx.x & 255), lsum);
}

// K_enc: fillBuffer-style streaming writer of the one-hot matrix (zeros AND ones
// in one pass). Region is 8B-aligned; chunks are the aligned f32x4 span, head/tail
// 2 floats handled specially. Chunk c covers floats g..g+3, g = 4c+2 (rel. to enc
// start); col = g & 511 is ≡2 mod 4, so col==510 chunks straddle rows.
__global__ __launch_bounds__(256) void vq_enc(const float* __restrict__ ws,
                                              float* __restrict__ out) {
    const int t = threadIdx.x;
    const int* __restrict__ idx = (const int*)ws + IDX_W;
    f32x4* __restrict__ dst = (f32x4*)(out + OUT_E_OFF + 2);
    const int base = blockIdx.x * 8192;          // 256 threads * 32 chunks
#pragma unroll 4
    for (int i = 0; i < 32; ++i) {
        int c = base + i * 256 + t;
        if (c < 16777215) {
            int g   = c * 4 + 2;
            int row = g >> 9;
            int col = g & 511;
            int k   = idx[row];
            f32x4 v;
            if (col == 510) {
                int k2 = idx[row + 1];
                v.x = (k  == 510) ? 1.f : 0.f;
                v.y = (k  == 511) ? 1.f : 0.f;
                v.z = (k2 == 0)   ? 1.f : 0.f;
                v.w = (k2 == 1)   ? 1.f : 0.f;
            } else {
                v.x = (col     == k) ? 1.f : 0.f;
                v.y = (col + 1 == k) ? 1.f : 0.f;
                v.z = (col + 2 == k) ? 1.f : 0.f;
                v.w = (col + 3 == k) ? 1.f : 0.f;
            }
            dst[c] = v;
        }
    }
    if (blockIdx.x == 0 && t == 0) {
        int k0 = idx[0];
        f32x2 hd; hd.x = (k0 == 0) ? 1.f : 0.f; hd.y = (k0 == 1) ? 1.f : 0.f;
        *(f32x2*)(out + OUT_E_OFF) = hd;
        int kl = idx[131071];
        f32x2 tl; tl.x = (kl == 510) ? 1.f : 0.f; tl.y = (kl == 511) ? 1.f : 0.f;
        *(f32x2*)(out + OUT_E_OFF + (size_t)131071 * 512 + 510) = tl;
    }
}

__global__ __launch_bounds__(512) void vq_fin(const float* __restrict__ ws, float* __restrict__ out) {
    __shared__ float redP[8], redL[8];
    const int t = threadIdx.x;
    const unsigned* counts = (const unsigned*)ws + 256;
    float p = (float)counts[t] * (1.0f / 131072.0f);
    float s = p * logf(p + 1e-10f);
    float lp = (t < 256) ? ws[t] : 0.f;
#pragma unroll
    for (int off = 32; off >= 1; off >>= 1) {
        s  += __shfl_down(s, off);
        lp += __shfl_down(lp, off);
    }
    if ((t & 63) == 0) { redP[t >> 6] = s; redL[t >> 6] = lp; }
    __syncthreads();
    if (t == 0) {
        float tp = 0.f, tl = 0.f;
#pragma unroll
        for (int i = 0; i < 8; ++i) { tp += redP[i]; tl += redL[i]; }
        out[OUT_P_OFF] = expf(-tp);
        out[0] = tl * (1.25f / 8388608.0f);
    }
}

extern "C" void kernel_launch(void* const* d_in, const int* in_sizes, int n_in,
                              void* d_out, int out_size, void* d_ws, size_t ws_size,
                              hipStream_t stream) {
    const float* X = (const float*)d_in[0];
    const float* W = (const float*)d_in[1];
    float* out = (float*)d_out;
    float* ws  = (float*)d_ws;

    (void)hipMemsetAsync(d_ws, 0, 768 * sizeof(float), stream);   // loss slots + counts
    vq_init<<<9, 512, 0, stream>>>(W, ws);
    vq_score<<<8192, 64, 0, stream>>>(X, W, out, ws);
    vq_enc<<<2048, 256, 0, stream>>>(ws, out);
    vq_fin<<<1, 512, 0, stream>>>(ws, out);
}

// Round 8
// 158.141 us; speedup vs baseline: 1.0491x; 1.0491x over previous
//
#include <hip/hip_runtime.h>

// VQ-VAE vector quantizer. N=131072 rows (32*64*64), D=64, K=512.
// X: NCHW f32 (32,64,64,64); W: (512,64) f32.
// out: [0]=loss, [1..8388609)=quantized NCHW, [8388609]=perplexity,
//      [8388610..)=one-hot encodings [131072][512].
#define BHW 262144
#define OUT_Q_OFF 1
#define OUT_P_OFF 8388609
#define OUT_E_OFF 8388610

// ws layout (4-byte words):
// [0..256)      loss partial slots (f32)   -- memset 0
// [256..768)    counts (u32)               -- memset 0
// [768..1280)   wsq = ||e_k||^2 (f32)
// [1280..17664) bf16 codebook B-fragments, PRE-SCALED by -2: [tn=32][j=2][lane=64] x 8

typedef __attribute__((ext_vector_type(8))) short short8;
typedef __attribute__((ext_vector_type(4))) float f32x4;

__device__ __forceinline__ unsigned short f2bf(float f) {
    union { float f; unsigned u; } c; c.f = f;
    unsigned r = (c.u + 0x7FFFu + ((c.u >> 16) & 1u)) >> 16;  // RNE
    return (unsigned short)r;
}

__global__ __launch_bounds__(512) void vq_init(const float* __restrict__ W, float* __restrict__ ws) {
    const int tid = blockIdx.x * 512 + threadIdx.x;
    if (tid < 512) {
        const float4* W4 = (const float4*)W;
        float s = 0.f;
#pragma unroll
        for (int i = 0; i < 16; ++i) {
            float4 v = W4[tid * 16 + i];
            s = fmaf(v.x, v.x, s); s = fmaf(v.y, v.y, s);
            s = fmaf(v.z, v.z, s); s = fmaf(v.w, v.w, s);
        }
        ws[768 + tid] = s;
    } else {
        // B-fragment pre-swizzle (scaled by -2): chunk c -> (tn, j, lane)
        const int c  = tid - 512;            // 0..4095
        const int l  = c & 63;
        const int j  = (c >> 6) & 1;
        const int tn = c >> 7;
        const int n  = tn * 16 + (l & 15);
        const int k0 = j * 32 + ((l >> 4) & 3) * 8;
        const float* src = W + n * 64 + k0;
        unsigned h0 = f2bf(-2.f * src[0]) | ((unsigned)f2bf(-2.f * src[1]) << 16);
        unsigned h1 = f2bf(-2.f * src[2]) | ((unsigned)f2bf(-2.f * src[3]) << 16);
        unsigned h2 = f2bf(-2.f * src[4]) | ((unsigned)f2bf(-2.f * src[5]) << 16);
        unsigned h3 = f2bf(-2.f * src[6]) | ((unsigned)f2bf(-2.f * src[7]) << 16);
        uint4* dst = (uint4*)(ws + 1280);
        dst[c] = make_uint4(h0, h1, h2, h3);
    }
}

// vq_score: one wave per block, 16 rows. MFMA argmin -> quantized_st, loss,
// histogram, and the 16 scattered 1.0f one-hot stores (zeros come from the
// preceding 268MB hipMemsetAsync, which runs at rocclr-fill rate).
__global__ __launch_bounds__(64) void vq_score(const float* __restrict__ X,
                                               const float* __restrict__ W,
                                               float* __restrict__ out,
                                               float* __restrict__ ws) {
    const int l    = threadIdx.x;        // 0..63
    const int nlow = l & 15;
    const int kg   = l >> 4;
    const int rowbase = blockIdx.x * 16; // 16 consecutive rows, same (b,h)
    const int b  = rowbase >> 12;
    const int h  = (rowbase >> 6) & 63;
    const int w0 = rowbase & 63;

    // this lane's x row (A-frag row = nlow), dims (kg,e); kept for epilogue
    const float* xr = X + (size_t)b * BHW + (size_t)h * 64 + (w0 + nlow);
    float xf[16];
#pragma unroll
    for (int e = 0; e < 8; ++e) xf[e]     = xr[(size_t)(kg * 8 + e) * 4096];
#pragma unroll
    for (int e = 0; e < 8; ++e) xf[8 + e] = xr[(size_t)(32 + kg * 8 + e) * 4096];
    short8 a0, a1;
#pragma unroll
    for (int e = 0; e < 8; ++e) { a0[e] = (short)f2bf(xf[e]); a1[e] = (short)f2bf(xf[8 + e]); }

    // scan all 512 codes: score = wsq (C-init) + (-2e)·x via MFMA
    const short8* __restrict__ B8  = (const short8*)(ws + 1280);
    const float*  __restrict__ wsq = ws + 768;
    float bS[4]; int bK[4];
#pragma unroll
    for (int r = 0; r < 4; ++r) { bS[r] = 3.4e38f; bK[r] = 0; }

#pragma unroll 2
    for (int tn = 0; tn < 32; ++tn) {
        short8 f0 = B8[tn * 128 + l];
        short8 f1 = B8[tn * 128 + 64 + l];
        const float wq = wsq[tn * 16 + nlow];
        f32x4 acc = {wq, wq, wq, wq};
        acc = __builtin_amdgcn_mfma_f32_16x16x32_bf16(a0, f0, acc, 0, 0, 0);
        acc = __builtin_amdgcn_mfma_f32_16x16x32_bf16(a1, f1, acc, 0, 0, 0);
        const int n = tn * 16 + nlow;
#pragma unroll
        for (int r = 0; r < 4; ++r) {
            if (acc[r] < bS[r]) { bS[r] = acc[r]; bK[r] = n; }
        }
    }
    // butterfly min-reduce over 16 col-lanes per kg group (lowest-k tiebreak)
#pragma unroll
    for (int r = 0; r < 4; ++r) {
#pragma unroll
        for (int mask = 1; mask <= 8; mask <<= 1) {
            float os = __shfl_xor(bS[r], mask);
            int   ok = __shfl_xor(bK[r], mask);
            if (os < bS[r] || (os == bS[r] && ok < bK[r])) { bS[r] = os; bK[r] = ok; }
        }
    }

    // per-row best broadcast; one-hot 1.0 store + histogram (zeros pre-filled)
    int rowBk = 0;   // best for this lane's own row (nlow)
    int myBk  = 0;   // best for row l (lanes 0..15)
#pragma unroll
    for (int m = 0; m < 16; ++m) {
        int bkm = __shfl(bK[m & 3], (m >> 2) * 16);
        if (nlow == m) rowBk = bkm;
        if (l == m)    myBk = bkm;
    }
    if (l < 16) {
        out[OUT_E_OFF + (size_t)(rowbase + l) * 512 + myBk] = 1.0f;
        atomicAdd((unsigned*)ws + 256 + myBk, 1u);
    }

    // quantized_st + loss partials (x register-resident; W row L2-hot)
    const float4* W4 = (const float4*)W;
    float4 q0 = W4[rowBk * 16 + kg * 2];
    float4 q1 = W4[rowBk * 16 + kg * 2 + 1];
    float4 q2 = W4[rowBk * 16 + 8 + kg * 2];
    float4 q3 = W4[rowBk * 16 + 8 + kg * 2 + 1];
    float qv[16] = {q0.x, q0.y, q0.z, q0.w, q1.x, q1.y, q1.z, q1.w,
                    q2.x, q2.y, q2.z, q2.w, q3.x, q3.y, q3.z, q3.w};
    float lsum = 0.f;
    float* op = out + OUT_Q_OFF + (size_t)b * BHW + (size_t)h * 64 + (w0 + nlow);
#pragma unroll
    for (int e = 0; e < 8; ++e) {
        float d0 = qv[e] - xf[e];
        lsum = fmaf(d0, d0, lsum);
        op[(size_t)(kg * 8 + e) * 4096] = xf[e] + d0;
        float d1 = qv[8 + e] - xf[8 + e];
        lsum = fmaf(d1, d1, lsum);
        op[(size_t)(32 + kg * 8 + e) * 4096] = xf[8 + e] + d1;
    }

    // loss wave-reduce; spread atomics over 256 slots
#pragma unroll
    for (int off = 32; off >= 1; off >>= 1) lsum += __shfl_down(lsum, off);
    if (l == 0) atomicAdd(ws + (blockIdx.x & 255), lsum);
}

__global__ __launch_bounds__(512) void vq_fin(const float* __restrict__ ws, float* __restrict__ out) {
    __shared__ float redP[8], redL[8];
    const int t = threadIdx.x;
    const unsigned* counts = (const unsigned*)ws + 256;
    float p = (float)counts[t] * (1.0f / 131072.0f);
    float s = p * logf(p + 1e-10f);
    float lp = (t < 256) ? ws[t] : 0.f;
#pragma unroll
    for (int off = 32; off >= 1; off >>= 1) {
        s  += __shfl_down(s, off);
        lp += __shfl_down(lp, off);
    }
    if ((t & 63) == 0) { redP[t >> 6] = s; redL[t >> 6] = lp; }
    __syncthreads();
    if (t == 0) {
        float tp = 0.f, tl = 0.f;
#pragma unroll
        for (int i = 0; i < 8; ++i) { tp += redP[i]; tl += redL[i]; }
        out[OUT_P_OFF] = expf(-tp);
        out[0] = tl * (1.25f / 8388608.0f);
    }
}

extern "C" void kernel_launch(void* const* d_in, const int* in_sizes, int n_in,
                              void* d_out, int out_size, void* d_ws, size_t ws_size,
                              hipStream_t stream) {
    const float* X = (const float*)d_in[0];
    const float* W = (const float*)d_in[1];
    float* out = (float*)d_out;
    float* ws  = (float*)d_ws;

    (void)hipMemsetAsync(d_ws, 0, 768 * sizeof(float), stream);          // loss slots + counts
    // Bulk-zero the one-hot region via rocclr fill (proven 6.6 TB/s on this buffer).
    (void)hipMemsetAsync(out + OUT_E_OFF, 0, (size_t)131072 * 512 * sizeof(float), stream);
    vq_init<<<9, 512, 0, stream>>>(W, ws);
    vq_score<<<8192, 64, 0, stream>>>(X, W, out, ws);
    vq_fin<<<1, 512, 0, stream>>>(ws, out);
}

// Round 9
// 111.348 us; speedup vs baseline: 1.4899x; 1.4202x over previous
//
#include <hip/hip_runtime.h>

// VQ-VAE vector quantizer. N=131072 rows (32*64*64), D=64, K=512.
// X: NCHW f32 (32,64,64,64); W: (512,64) f32.
// out: [0]=loss, [1..8388609)=quantized NCHW, [8388609]=perplexity,
//      [8388610..)=one-hot encodings [131072][512].
#define BHW 262144
#define OUT_Q_OFF 1
#define OUT_P_OFF 8388609
#define OUT_E_OFF 8388610

// ws layout (4-byte words):
// [0..256)      loss partial slots (f32)   -- memset 0
// [256..768)    counts (u32)               -- memset 0
// [768..1280)   wsq = ||e_k||^2 (f32)
// [1280..17664) bf16 codebook B-fragments, PRE-SCALED by -2: [tn=32][j=2][lane=64] x 8

typedef __attribute__((ext_vector_type(8))) short short8;
typedef __attribute__((ext_vector_type(4))) float f32x4;
typedef __attribute__((ext_vector_type(2))) float f32x2;

__device__ __forceinline__ unsigned short f2bf(float f) {
    union { float f; unsigned u; } c; c.f = f;
    unsigned r = (c.u + 0x7FFFu + ((c.u >> 16) & 1u)) >> 16;  // RNE
    return (unsigned short)r;
}

__global__ __launch_bounds__(512) void vq_init(const float* __restrict__ W, float* __restrict__ ws) {
    const int tid = blockIdx.x * 512 + threadIdx.x;
    if (tid < 512) {
        const float4* W4 = (const float4*)W;
        float s = 0.f;
#pragma unroll
        for (int i = 0; i < 16; ++i) {
            float4 v = W4[tid * 16 + i];
            s = fmaf(v.x, v.x, s); s = fmaf(v.y, v.y, s);
            s = fmaf(v.z, v.z, s); s = fmaf(v.w, v.w, s);
        }
        ws[768 + tid] = s;
    } else {
        // B-fragment pre-swizzle (scaled by -2): chunk c -> (tn, j, lane)
        const int c  = tid - 512;            // 0..4095
        const int l  = c & 63;
        const int j  = (c >> 6) & 1;
        const int tn = c >> 7;
        const int n  = tn * 16 + (l & 15);
        const int k0 = j * 32 + ((l >> 4) & 3) * 8;
        const float* src = W + n * 64 + k0;
        unsigned h0 = f2bf(-2.f * src[0]) | ((unsigned)f2bf(-2.f * src[1]) << 16);
        unsigned h1 = f2bf(-2.f * src[2]) | ((unsigned)f2bf(-2.f * src[3]) << 16);
        unsigned h2 = f2bf(-2.f * src[4]) | ((unsigned)f2bf(-2.f * src[5]) << 16);
        unsigned h3 = f2bf(-2.f * src[6]) | ((unsigned)f2bf(-2.f * src[7]) << 16);
        uint4* dst = (uint4*)(ws + 1280);
        dst[c] = make_uint4(h0, h1, h2, h3);
    }
}

// vq_main: 256 threads = 4 waves, 64 rows (one (b,h) w-line). B-table staged
// into LDS in 32KB halves (shared by all 4 waves); MFMA feeds from ds_read_b128.
// Encodings written inline (proven free, R5 vs R8). One-hot zeros included.
__global__ __launch_bounds__(256) void vq_main(const float* __restrict__ X,
                                               const float* __restrict__ W,
                                               float* __restrict__ out,
                                               float* __restrict__ ws) {
    const int t    = threadIdx.x;
    const int l    = t & 63;
    const int wv   = t >> 6;
    const int nlow = l & 15;
    const int kg   = l >> 4;
    const int rowbase = blockIdx.x * 64;     // full w-line, shared (b,h)
    const int b = rowbase >> 12;
    const int h = (rowbase >> 6) & 63;
    const int myrow = wv * 16 + nlow;        // this lane's w (A-frag row = nlow)

    __shared__ short8 Btab[2048];            // 32 KB: half of the B-fragment table

    // ---- this lane's x row, dims (kg,e); kept in registers for epilogue ----
    const float* xr = X + (size_t)b * BHW + (size_t)h * 64 + myrow;
    float xf[16];
#pragma unroll
    for (int e = 0; e < 8; ++e) xf[e]     = xr[(size_t)(kg * 8 + e) * 4096];
#pragma unroll
    for (int e = 0; e < 8; ++e) xf[8 + e] = xr[(size_t)(32 + kg * 8 + e) * 4096];
    short8 a0, a1;
#pragma unroll
    for (int e = 0; e < 8; ++e) { a0[e] = (short)f2bf(xf[e]); a1[e] = (short)f2bf(xf[8 + e]); }

    // ---- scan all 512 codes from LDS-staged table ----
    const uint4* __restrict__ gtab = (const uint4*)(ws + 1280);
    const float* __restrict__ wsq  = ws + 768;
    float bS[4]; int bK[4];
#pragma unroll
    for (int r = 0; r < 4; ++r) { bS[r] = 3.4e38f; bK[r] = 0; }

    for (int half = 0; half < 2; ++half) {
        __syncthreads();                     // safe reuse of Btab
        uint4* bt = (uint4*)Btab;
#pragma unroll
        for (int i = 0; i < 8; ++i)
            bt[i * 256 + t] = gtab[half * 2048 + i * 256 + t];
        __syncthreads();
#pragma unroll 4
        for (int tn = 0; tn < 16; ++tn) {
            short8 f0 = Btab[tn * 128 + l];
            short8 f1 = Btab[tn * 128 + 64 + l];
            const int   n  = (half * 16 + tn) * 16 + nlow;
            const float wq = wsq[n];
            f32x4 acc = {wq, wq, wq, wq};
            acc = __builtin_amdgcn_mfma_f32_16x16x32_bf16(a0, f0, acc, 0, 0, 0);
            acc = __builtin_amdgcn_mfma_f32_16x16x32_bf16(a1, f1, acc, 0, 0, 0);
#pragma unroll
            for (int r = 0; r < 4; ++r) {
                if (acc[r] < bS[r]) { bS[r] = acc[r]; bK[r] = n; }
            }
        }
    }
    // butterfly min-reduce over 16 col-lanes per kg group (lowest-k tiebreak)
#pragma unroll
    for (int r = 0; r < 4; ++r) {
#pragma unroll
        for (int mask = 1; mask <= 8; mask <<= 1) {
            float os = __shfl_xor(bS[r], mask);
            int   ok = __shfl_xor(bK[r], mask);
            if (os < bS[r] || (os == bS[r] && ok < bK[r])) { bS[r] = os; bK[r] = ok; }
        }
    }

    // ---- per-row best broadcast; inline one-hot writes; histogram ----
    int rowBk = 0;   // best for this lane's own row (nlow)
    int myBk  = 0;   // best for row l within this wave's 16 (lanes 0..15)
    f32x2* encB = (f32x2*)(out + OUT_E_OFF);
    const size_t Rbase = (size_t)(rowbase + wv * 16);
#pragma unroll
    for (int m = 0; m < 16; ++m) {
        int bkm = __shfl(bK[m & 3], (m >> 2) * 16);
        if (nlow == m) rowBk = bkm;
        if (l == m)    myBk = bkm;
        f32x2* erow = encB + (Rbase + m) * 256;
#pragma unroll
        for (int c = 0; c < 4; ++c) {
            int p = c * 64 + l;
            f32x2 v;
            v.x = (bkm == 2 * p)     ? 1.f : 0.f;
            v.y = (bkm == 2 * p + 1) ? 1.f : 0.f;
            erow[p] = v;
        }
    }
    if (l < 16) atomicAdd((unsigned*)ws + 256 + myBk, 1u);

    // ---- quantized_st + loss partials (x register-resident; W row L2-hot) ----
    const float4* W4 = (const float4*)W;
    float4 q0 = W4[rowBk * 16 + kg * 2];
    float4 q1 = W4[rowBk * 16 + kg * 2 + 1];
    float4 q2 = W4[rowBk * 16 + 8 + kg * 2];
    float4 q3 = W4[rowBk * 16 + 8 + kg * 2 + 1];
    float qv[16] = {q0.x, q0.y, q0.z, q0.w, q1.x, q1.y, q1.z, q1.w,
                    q2.x, q2.y, q2.z, q2.w, q3.x, q3.y, q3.z, q3.w};
    float lsum = 0.f;
    float* op = out + OUT_Q_OFF + (size_t)b * BHW + (size_t)h * 64 + myrow;
#pragma unroll
    for (int e = 0; e < 8; ++e) {
        float d0 = qv[e] - xf[e];
        lsum = fmaf(d0, d0, lsum);
        op[(size_t)(kg * 8 + e) * 4096] = xf[e] + d0;
        float d1 = qv[8 + e] - xf[8 + e];
        lsum = fmaf(d1, d1, lsum);
        op[(size_t)(32 + kg * 8 + e) * 4096] = xf[8 + e] + d1;
    }

    // ---- loss wave-reduce; spread atomics over 256 slots ----
#pragma unroll
    for (int off = 32; off >= 1; off >>= 1) lsum += __shfl_down(lsum, off);
    if (l == 0) atomicAdd(ws + ((blockIdx.x * 4 + wv) & 255), lsum);
}

__global__ __launch_bounds__(512) void vq_fin(const float* __restrict__ ws, float* __restrict__ out) {
    __shared__ float redP[8], redL[8];
    const int t = threadIdx.x;
    const unsigned* counts = (const unsigned*)ws + 256;
    float p = (float)counts[t] * (1.0f / 131072.0f);
    float s = p * logf(p + 1e-10f);
    float lp = (t < 256) ? ws[t] : 0.f;
#pragma unroll
    for (int off = 32; off >= 1; off >>= 1) {
        s  += __shfl_down(s, off);
        lp += __shfl_down(lp, off);
    }
    if ((t & 63) == 0) { redP[t >> 6] = s; redL[t >> 6] = lp; }
    __syncthreads();
    if (t == 0) {
        float tp = 0.f, tl = 0.f;
#pragma unroll
        for (int i = 0; i < 8; ++i) { tp += redP[i]; tl += redL[i]; }
        out[OUT_P_OFF] = expf(-tp);
        out[0] = tl * (1.25f / 8388608.0f);
    }
}

extern "C" void kernel_launch(void* const* d_in, const int* in_sizes, int n_in,
                              void* d_out, int out_size, void* d_ws, size_t ws_size,
                              hipStream_t stream) {
    const float* X = (const float*)d_in[0];
    const float* W = (const float*)d_in[1];
    float* out = (float*)d_out;
    float* ws  = (float*)d_ws;

    (void)hipMemsetAsync(d_ws, 0, 768 * sizeof(float), stream);   // loss slots + counts
    vq_init<<<9, 512, 0, stream>>>(W, ws);
    vq_main<<<2048, 256, 0, stream>>>(X, W, out, ws);
    vq_fin<<<1, 512, 0, stream>>>(ws, out);
}